// Round 3
// baseline (318.652 us; speedup 1.0000x reference)
//
#include <hip/hip_runtime.h>
#include <hip/hip_bf16.h>

#define BB 2
#define CC 512
#define GG 32
#define NN 4096
#define EPSV 1e-6f

typedef __attribute__((ext_vector_type(4))) float f32x4;
typedef __attribute__((ext_vector_type(8))) short s16x8;
typedef __attribute__((ext_vector_type(4))) short s16x4;

__device__ __forceinline__ ushort f2bf(float f){
  union { float f; unsigned u; } v; v.f = f;
  unsigned r = v.u + 0x7fffu + ((v.u >> 16) & 1u);
  return (ushort)(r >> 16);
}
__device__ __forceinline__ short f2bfs(float f){ return (short)f2bf(f); }

__device__ __forceinline__ f32x4 mfma16(s16x8 a, s16x8 b, f32x4 c){
  return __builtin_amdgcn_mfma_f32_16x16x32_bf16(a, b, c, 0, 0, 0);
}

#define GLOAD_LDS16(g, l) __builtin_amdgcn_global_load_lds( \
    (const __attribute__((address_space(1))) void*)(g),     \
    (__attribute__((address_space(3))) void*)(l), 16, 0, 0)

// ---------------- weight fp32 -> bf16 ----------------
__global__ __launch_bounds__(256) void k_convert_w(const float* __restrict__ wq, const float* __restrict__ wk,
                                                   const float* __restrict__ wv, const float* __restrict__ wp,
                                                   ushort* __restrict__ wbf){
  int idx = blockIdx.x * 256 + threadIdx.x;
  const float* srcs[4] = {wq, wk, wv, wp};
  #pragma unroll
  for (int m = 0; m < 4; m++){
    float4 v = reinterpret_cast<const float4*>(srcs[m])[idx];
    ushort4 o; o.x = f2bf(v.x); o.y = f2bf(v.y); o.z = f2bf(v.z); o.w = f2bf(v.w);
    reinterpret_cast<ushort4*>(wbf + (size_t)m * CC * CC)[idx] = o;
  }
}

// ---------------- GroupNorm stats ----------------
__global__ __launch_bounds__(256) void k_gn_stats(const float* __restrict__ x, float* __restrict__ stats){
  int bg = blockIdx.x;  // 0..63
  const float* p = x + (size_t)bg * (16 * NN);
  float s = 0.f, ss = 0.f;
  for (int i = threadIdx.x; i < 16 * NN / 4; i += 256){
    float4 v = reinterpret_cast<const float4*>(p)[i];
    s  += v.x + v.y + v.z + v.w;
    ss += v.x*v.x + v.y*v.y + v.z*v.z + v.w*v.w;
  }
  #pragma unroll
  for (int off = 32; off; off >>= 1){ s += __shfl_down(s, off); ss += __shfl_down(ss, off); }
  __shared__ float rs_[4], rss_[4];
  int w = threadIdx.x >> 6, lane = threadIdx.x & 63;
  if (lane == 0){ rs_[w] = s; rss_[w] = ss; }
  __syncthreads();
  if (threadIdx.x == 0){
    float S = rs_[0] + rs_[1] + rs_[2] + rs_[3];
    float SS = rss_[0] + rss_[1] + rss_[2] + rss_[3];
    float inv = 1.0f / (16.0f * NN);
    float mean = S * inv;
    float var = SS * inv - mean * mean;
    stats[bg * 2 + 0] = mean;
    stats[bg * 2 + 1] = rsqrtf(var + EPSV);
  }
}

// ---------------- GN apply + transpose: x[b][c][n] -> hf_t[b][n][c] bf16 ----------------
__global__ __launch_bounds__(256) void k_gn_apply(const float* __restrict__ x, const float* __restrict__ gsc,
                                                  const float* __restrict__ gbi, const float* __restrict__ stats,
                                                  ushort* __restrict__ hf){
  __shared__ ushort tr[32][520];
  int b = blockIdx.y;
  int nb = blockIdx.x * 32;
  int t = threadIdx.x;
  int n = t & 31, cr = t >> 5;
  const float* xb = x + (size_t)b * CC * NN;
  for (int c0 = 0; c0 < CC; c0 += 8){
    int c = c0 + cr;
    float mean = stats[(b * GG + (c >> 4)) * 2 + 0];
    float rstd = stats[(b * GG + (c >> 4)) * 2 + 1];
    float v = xb[(size_t)c * NN + nb + n];
    tr[n][c] = f2bf((v - mean) * rstd * gsc[c] + gbi[c]);
  }
  __syncthreads();
  ushort* out = hf + ((size_t)b * NN + nb) * CC;
  int c8 = (t & 63) * 8;
  int nrow0 = t >> 6;
  #pragma unroll
  for (int i = 0; i < 8; i++){
    int nr = nrow0 + i * 4;
    *reinterpret_cast<s16x8*>(&out[(size_t)nr * CC + c8]) =
      *reinterpret_cast<const s16x8*>(&tr[nr][c8]);
  }
}

// ---------------- GEMM: out[o][n] = W[o][:] . Bt[n][:] + bias[o] ----------------
template<int MODE>
__global__ __launch_bounds__(256) void k_gemm(const ushort* __restrict__ A, const ushort* __restrict__ Bt,
                                              const float* __restrict__ bias, ushort* __restrict__ o16,
                                              float* __restrict__ o32, const float* __restrict__ xres,
                                              float scl){
  __shared__ ushort Al[64][72];
  __shared__ ushort Bl[64][72];
  __shared__ float bl[64];
  __shared__ float trf[MODE == 2 ? 64 * 68 : 1];
  int b = blockIdx.z, ob = blockIdx.y * 64, nb = blockIdx.x * 64;
  int t = threadIdx.x, w = t >> 6, l = t & 63;
  int lr = l & 15, lk = l >> 4;
  int wo = (w >> 1) * 32, wn = (w & 1) * 32;
  if (t < 64) bl[t] = bias[ob + t];
  const ushort* Bp = Bt + ((size_t)b * NN + nb) * CC;
  const ushort* Ap = A + (size_t)ob * CC;
  int srow = t >> 2, scol = (t & 3) * 16;
  f32x4 acc[2][2] = {};
  for (int k0 = 0; k0 < CC; k0 += 64){
    *reinterpret_cast<s16x8*>(&Al[srow][scol])     = *reinterpret_cast<const s16x8*>(&Ap[(size_t)srow * CC + k0 + scol]);
    *reinterpret_cast<s16x8*>(&Al[srow][scol + 8]) = *reinterpret_cast<const s16x8*>(&Ap[(size_t)srow * CC + k0 + scol + 8]);
    *reinterpret_cast<s16x8*>(&Bl[srow][scol])     = *reinterpret_cast<const s16x8*>(&Bp[(size_t)srow * CC + k0 + scol]);
    *reinterpret_cast<s16x8*>(&Bl[srow][scol + 8]) = *reinterpret_cast<const s16x8*>(&Bp[(size_t)srow * CC + k0 + scol + 8]);
    __syncthreads();
    #pragma unroll
    for (int kk = 0; kk < 2; kk++){
      s16x8 a0 = *reinterpret_cast<const s16x8*>(&Al[wo + lr][kk * 32 + lk * 8]);
      s16x8 a1 = *reinterpret_cast<const s16x8*>(&Al[wo + 16 + lr][kk * 32 + lk * 8]);
      s16x8 b0 = *reinterpret_cast<const s16x8*>(&Bl[wn + lr][kk * 32 + lk * 8]);
      s16x8 b1 = *reinterpret_cast<const s16x8*>(&Bl[wn + 16 + lr][kk * 32 + lk * 8]);
      acc[0][0] = mfma16(a0, b0, acc[0][0]);
      acc[0][1] = mfma16(a0, b1, acc[0][1]);
      acc[1][0] = mfma16(a1, b0, acc[1][0]);
      acc[1][1] = mfma16(a1, b1, acc[1][1]);
    }
    __syncthreads();
  }
  if (MODE == 0){
    #pragma unroll
    for (int oi = 0; oi < 2; oi++)
      #pragma unroll
      for (int nj = 0; nj < 2; nj++){
        int o0 = wo + oi * 16 + lk * 4;
        int n  = nb + wn + nj * 16 + lr;
        s16x4 pv;
        #pragma unroll
        for (int r = 0; r < 4; r++) pv[r] = f2bfs((acc[oi][nj][r] + bl[o0 + r]) * scl);
        *reinterpret_cast<s16x4*>(&o16[((size_t)b * NN + n) * CC + ob + o0]) = pv;
      }
  } else if (MODE == 1){
    #pragma unroll
    for (int oi = 0; oi < 2; oi++)
      #pragma unroll
      for (int nj = 0; nj < 2; nj++){
        int o0 = wo + oi * 16 + lk * 4;
        int ncl = wn + nj * 16 + lr;
        #pragma unroll
        for (int r = 0; r < 4; r++) Al[o0 + r][ncl] = f2bf(acc[oi][nj][r] + bl[o0 + r]);
      }
    __syncthreads();
    {
      int o = t >> 2, ns = (t & 3) * 16;
      ushort* dst = &o16[((size_t)b * CC + ob + o) * NN + nb + ns];
      *reinterpret_cast<s16x8*>(dst)     = *reinterpret_cast<const s16x8*>(&Al[o][ns]);
      *reinterpret_cast<s16x8*>(dst + 8) = *reinterpret_cast<const s16x8*>(&Al[o][ns + 8]);
    }
  } else {
    #pragma unroll
    for (int oi = 0; oi < 2; oi++)
      #pragma unroll
      for (int nj = 0; nj < 2; nj++){
        int o0 = wo + oi * 16 + lk * 4;
        int ncl = wn + nj * 16 + lr;
        #pragma unroll
        for (int r = 0; r < 4; r++) trf[(o0 + r) * 68 + ncl] = acc[oi][nj][r] + bl[o0 + r];
      }
    __syncthreads();
    {
      int o = t >> 2, ns = (t & 3) * 16;
      size_t base = ((size_t)b * CC + ob + o) * NN + nb + ns;
      #pragma unroll
      for (int q = 0; q < 4; q++){
        float4 xv = *reinterpret_cast<const float4*>(&xres[base + q * 4]);
        float4 ov;
        ov.x = xv.x + trf[o * 68 + ns + q * 4 + 0];
        ov.y = xv.y + trf[o * 68 + ns + q * 4 + 1];
        ov.z = xv.z + trf[o * 68 + ns + q * 4 + 2];
        ov.w = xv.w + trf[o * 68 + ns + q * 4 + 3];
        *reinterpret_cast<float4*>(&o32[base + q * 4]) = ov;
      }
    }
  }
}

// ---------------- flash attention v3 ----------------
// v2 + (a) V prefetch hoisted to top of iter (hides L2 latency under S+softmax),
// (b) defer-max rescale THR=8 (skips the 128-mul O rescale on stable iters),
// (c) 4-way ILP in S accumulation, (d) s_setprio around MFMA clusters.
__global__ __launch_bounds__(256, 2) void k_attn2(const ushort* __restrict__ qt, const ushort* __restrict__ kt,
                                                  const ushort* __restrict__ vv, ushort* __restrict__ ot,
                                                  float* __restrict__ opart, float* __restrict__ mpart,
                                                  float* __restrict__ lpart, int nsplit){
  __shared__ ushort Kl[2][32][512];   // rows 1KB; LDS[j][x] holds K[j][x ^ (j&7)] (16B chunks)
  __shared__ ushort Pl[64][40];
  __shared__ float cl[64], llds[64];
  __shared__ int sfl[4];
  int b = blockIdx.z, s = blockIdx.y, ib = blockIdx.x * 64;
  int t = threadIdx.x, w = t >> 6, l = t & 63;
  int lr = l & 15, lk = l >> 4;
  int jlen = NN / nsplit;
  int jbase = s * jlen;
  int niter = jlen / 32;
  const ushort* qb = qt + ((size_t)b * NN + ib) * CC;
  const ushort* kb = kt + (size_t)b * NN * CC;
  const ushort* vb = vv + (size_t)b * CC * NN;

  s16x8 qf[16];
  #pragma unroll
  for (int k = 0; k < 16; k++)
    qf[k] = *reinterpret_cast<const s16x8*>(&qb[(size_t)(w * 16 + lr) * CC + k * 32 + lk * 8]);

  f32x4 oc[8][4] = {};   // [ct][it]: O[c = w*128+ct*16+lk*4+r][i = it*16+lr]
  float m_run = -1e30f, l_run = 0.f;

  #pragma unroll
  for (int q = 0; q < 8; q++){
    int j = q * 4 + w;
    const ushort* src = kb + (size_t)(jbase + j) * CC + ((l ^ (j & 7)) << 3);
    GLOAD_LDS16(src, &Kl[0][j][0]);
  }
  __syncthreads();
  int cur = 0;
  for (int it = 0; it < niter; it++){
    int j0 = jbase + it * 32;
    // prefetch next K tile (completes at next barrier's vmcnt drain)
    if (it + 1 < niter){
      #pragma unroll
      for (int q = 0; q < 8; q++){
        int j = q * 4 + w;
        const ushort* src = kb + (size_t)(j0 + 32 + j) * CC + ((l ^ (j & 7)) << 3);
        GLOAD_LDS16(src, &Kl[cur ^ 1][j][0]);
      }
    }
    // prefetch THIS iter's V fragments (used in PV, ~600cy later)
    s16x8 vf[8];
    #pragma unroll
    for (int ct = 0; ct < 8; ct++)
      vf[ct] = *reinterpret_cast<const s16x8*>(&vb[(size_t)(w * 128 + ct * 16 + lr) * NN + j0 + lk * 8]);
    // S^T = K.Q : 4-way ILP (even/odd k partials)
    f32x4 sa0 = {0.f,0.f,0.f,0.f}, sa1 = {0.f,0.f,0.f,0.f};
    f32x4 sb0 = {0.f,0.f,0.f,0.f}, sb1 = {0.f,0.f,0.f,0.f};
    __builtin_amdgcn_s_setprio(1);
    #pragma unroll
    for (int k = 0; k < 16; k += 2){
      int x0 = ((k * 4 + lk) ^ (lr & 7)) << 3;
      int x1 = (((k + 1) * 4 + lk) ^ (lr & 7)) << 3;
      s16x8 k00 = *reinterpret_cast<const s16x8*>(&Kl[cur][lr][x0]);
      s16x8 k10 = *reinterpret_cast<const s16x8*>(&Kl[cur][16 + lr][x0]);
      s16x8 k01 = *reinterpret_cast<const s16x8*>(&Kl[cur][lr][x1]);
      s16x8 k11 = *reinterpret_cast<const s16x8*>(&Kl[cur][16 + lr][x1]);
      sa0 = mfma16(k00, qf[k], sa0);
      sb0 = mfma16(k10, qf[k], sb0);
      sa1 = mfma16(k01, qf[k + 1], sa1);
      sb1 = mfma16(k11, qf[k + 1], sb1);
    }
    __builtin_amdgcn_s_setprio(0);
    f32x4 sa, sb;
    #pragma unroll
    for (int r = 0; r < 4; r++){ sa[r] = sa0[r] + sa1[r]; sb[r] = sb0[r] + sb1[r]; }
    // in-register online softmax with defer-max (THR=8)
    float mx = fmaxf(fmaxf(fmaxf(sa[0], sa[1]), fmaxf(sa[2], sa[3])),
                     fmaxf(fmaxf(sb[0], sb[1]), fmaxf(sb[2], sb[3])));
    mx = fmaxf(mx, __shfl_xor(mx, 16));
    mx = fmaxf(mx, __shfl_xor(mx, 32));
    int need = __any(mx - m_run > 8.0f);
    float corr = 1.0f;
    if (need){
      float mnew = fmaxf(m_run, mx);
      corr = __expf(m_run - mnew);
      m_run = mnew;
    }
    float p[8];
    p[0] = __expf(sa[0] - m_run); p[1] = __expf(sa[1] - m_run);
    p[2] = __expf(sa[2] - m_run); p[3] = __expf(sa[3] - m_run);
    p[4] = __expf(sb[0] - m_run); p[5] = __expf(sb[1] - m_run);
    p[6] = __expf(sb[2] - m_run); p[7] = __expf(sb[3] - m_run);
    float ls = (p[0] + p[1]) + (p[2] + p[3]) + (p[4] + p[5]) + (p[6] + p[7]);
    ls += __shfl_xor(ls, 16);
    ls += __shfl_xor(ls, 32);
    l_run = l_run * corr + ls;
    s16x4 pA, pB;
    #pragma unroll
    for (int r = 0; r < 4; r++){ pA[r] = f2bfs(p[r]); pB[r] = f2bfs(p[4 + r]); }
    *reinterpret_cast<s16x4*>(&Pl[w * 16 + lr][lk * 4])      = pA;
    *reinterpret_cast<s16x4*>(&Pl[w * 16 + lr][16 + lk * 4]) = pB;
    if (lk == 0) cl[w * 16 + lr] = corr;
    if (l == 0)  sfl[w] = need;
    __syncthreads();
    // rescale O only when some wave's max moved
    int ra = sfl[0] | sfl[1] | sfl[2] | sfl[3];
    if (ra){
      float cr0 = cl[lr], cr1 = cl[16 + lr], cr2 = cl[32 + lr], cr3 = cl[48 + lr];
      #pragma unroll
      for (int ct = 0; ct < 8; ct++){
        #pragma unroll
        for (int r = 0; r < 4; r++){
          oc[ct][0][r] *= cr0; oc[ct][1][r] *= cr1;
          oc[ct][2][r] *= cr2; oc[ct][3][r] *= cr3;
        }
      }
    }
    s16x8 pf[4];
    #pragma unroll
    for (int it4 = 0; it4 < 4; it4++)
      pf[it4] = *reinterpret_cast<const s16x8*>(&Pl[it4 * 16 + lr][lk * 8]);
    __builtin_amdgcn_s_setprio(1);
    #pragma unroll
    for (int ct = 0; ct < 8; ct++){
      #pragma unroll
      for (int it4 = 0; it4 < 4; it4++)
        oc[ct][it4] = mfma16(vf[ct], pf[it4], oc[ct][it4]);
    }
    __builtin_amdgcn_s_setprio(0);
    __syncthreads();
    cur ^= 1;
  }
  if (lk == 0) llds[w * 16 + lr] = l_run;
  __syncthreads();
  if (nsplit == 1){
    #pragma unroll
    for (int it4 = 0; it4 < 4; it4++){
      float linv = 1.0f / llds[it4 * 16 + lr];
      #pragma unroll
      for (int ct = 0; ct < 8; ct++){
        s16x4 ov;
        #pragma unroll
        for (int r = 0; r < 4; r++) ov[r] = f2bfs(oc[ct][it4][r] * linv);
        *reinterpret_cast<s16x4*>(&ot[((size_t)b * NN + ib + it4 * 16 + lr) * CC + w * 128 + ct * 16 + lk * 4]) = ov;
      }
    }
  } else {
    #pragma unroll
    for (int it4 = 0; it4 < 4; it4++){
      size_t nrow = (size_t)(s * BB + b) * NN + ib + it4 * 16 + lr;
      #pragma unroll
      for (int ct = 0; ct < 8; ct++){
        f32x4 ov = oc[ct][it4];
        *reinterpret_cast<f32x4*>(&opart[nrow * CC + w * 128 + ct * 16 + lk * 4]) = ov;
      }
    }
    if (lk == 0){
      mpart[(size_t)(s * BB + b) * NN + ib + w * 16 + lr] = m_run;
      lpart[(size_t)(s * BB + b) * NN + ib + w * 16 + lr] = l_run;
    }
  }
}

// ---------------- combine j-split partials ----------------
__global__ __launch_bounds__(128) void k_combine(const float* __restrict__ opart, const float* __restrict__ mpart,
                                                 const float* __restrict__ lpart, ushort* __restrict__ ot, int S){
  int n = blockIdx.x, b = blockIdx.y;
  float M = -1e30f;
  for (int s = 0; s < S; s++) M = fmaxf(M, mpart[(size_t)(s * BB + b) * NN + n]);
  float L = 0.f;
  for (int s = 0; s < S; s++)
    L += lpart[(size_t)(s * BB + b) * NN + n] * __expf(mpart[(size_t)(s * BB + b) * NN + n] - M);
  float linv = 1.0f / L;
  int c = threadIdx.x * 4;
  f32x4 acc = {0.f, 0.f, 0.f, 0.f};
  for (int s = 0; s < S; s++){
    float wgt = __expf(mpart[(size_t)(s * BB + b) * NN + n] - M);
    f32x4 v = *reinterpret_cast<const f32x4*>(&opart[((size_t)(s * BB + b) * NN + n) * CC + c]);
    acc[0] += v[0] * wgt; acc[1] += v[1] * wgt; acc[2] += v[2] * wgt; acc[3] += v[3] * wgt;
  }
  s16x4 ov;
  #pragma unroll
  for (int r = 0; r < 4; r++) ov[r] = f2bfs(acc[r] * linv);
  *reinterpret_cast<s16x4*>(&ot[((size_t)b * NN + n) * CC + c]) = ov;
}

extern "C" void kernel_launch(void* const* d_in, const int* in_sizes, int n_in,
                              void* d_out, int out_size, void* d_ws, size_t ws_size,
                              hipStream_t stream){
  const float* x   = (const float*)d_in[0];
  const float* gsc = (const float*)d_in[1];
  const float* gbi = (const float*)d_in[2];
  const float* wq  = (const float*)d_in[3];
  const float* bq  = (const float*)d_in[4];
  const float* wk  = (const float*)d_in[5];
  const float* bk  = (const float*)d_in[6];
  const float* wv  = (const float*)d_in[7];
  const float* bv  = (const float*)d_in[8];
  const float* wp  = (const float*)d_in[9];
  const float* bp  = (const float*)d_in[10];
  char* ws = (char*)d_ws;
  const size_t MB = 1024 * 1024;
  ushort* wbf = (ushort*)ws;                       // 2 MB
  ushort* qtb = (ushort*)(ws + 2 * MB);            // 8 MB: q^T [b][n][c] (pre-scaled)
  ushort* ktb = (ushort*)(ws + 10 * MB);           // 8 MB: k^T [b][n][c]
  ushort* vvb = (ushort*)(ws + 18 * MB);           // 8 MB: v   [b][c][n]
  ushort* hfb = (ushort*)(ws + 26 * MB);           // 8 MB: hf^T / attn-out [b][n][c]
  float* stats = (float*)(ws + 34 * MB);           // 512 B
  float* mpart = (float*)(ws + 34 * MB + 4096);
  float* lpart = (float*)(ws + 34 * MB + 300 * 1024);
  float* opart = (float*)(ws + 35 * MB);           // S*16 MB
  ushort* otb = hfb;

  int S = (ws_size >= 99 * MB) ? 4 : (ws_size >= 67 * MB) ? 2 : 1;
  const float rs = 0.044194173824159216f;  // 512^-0.5

  k_convert_w<<<256, 256, 0, stream>>>(wq, wk, wv, wp, wbf);
  k_gn_stats<<<64, 256, 0, stream>>>(x, stats);
  k_gn_apply<<<dim3(128, 2, 1), 256, 0, stream>>>(x, gsc, gbi, stats, hfb);
  k_gemm<0><<<dim3(64, 8, 2), 256, 0, stream>>>(wbf,               hfb, bq, qtb, nullptr, nullptr, rs);
  k_gemm<0><<<dim3(64, 8, 2), 256, 0, stream>>>(wbf + CC * CC,     hfb, bk, ktb, nullptr, nullptr, 1.0f);
  k_gemm<1><<<dim3(64, 8, 2), 256, 0, stream>>>(wbf + 2 * CC * CC, hfb, bv, vvb, nullptr, nullptr, 1.0f);
  k_attn2<<<dim3(64, S, 2), 256, 0, stream>>>(qtb, ktb, vvb, otb, opart, mpart, lpart, S);
  if (S > 1)
    k_combine<<<dim3(NN, 2, 1), 128, 0, stream>>>(opart, mpart, lpart, otb, S);
  k_gemm<2><<<dim3(64, 8, 2), 256, 0, stream>>>(wbf + 3 * CC * CC, otb, bp, nullptr, (float*)d_out, x, 1.0f);
}

// Round 4
// 253.679 us; speedup vs baseline: 1.2561x; 1.2561x over previous
//
#include <hip/hip_runtime.h>
#include <hip/hip_bf16.h>

#define BB 2
#define CC 512
#define GG 32
#define NN 4096
#define EPSV 1e-6f

typedef __attribute__((ext_vector_type(4))) float f32x4;
typedef __attribute__((ext_vector_type(8))) short s16x8;
typedef __attribute__((ext_vector_type(4))) short s16x4;

__device__ __forceinline__ ushort f2bf(float f){
  union { float f; unsigned u; } v; v.f = f;
  unsigned r = v.u + 0x7fffu + ((v.u >> 16) & 1u);
  return (ushort)(r >> 16);
}
__device__ __forceinline__ short f2bfs(float f){ return (short)f2bf(f); }

__device__ __forceinline__ f32x4 mfma16(s16x8 a, s16x8 b, f32x4 c){
  return __builtin_amdgcn_mfma_f32_16x16x32_bf16(a, b, c, 0, 0, 0);
}

#define GLOAD_LDS16(g, l) __builtin_amdgcn_global_load_lds( \
    (const __attribute__((address_space(1))) void*)(g),     \
    (__attribute__((address_space(3))) void*)(l), 16, 0, 0)

// ---------------- weight fp32 -> bf16 ----------------
__global__ __launch_bounds__(256) void k_convert_w(const float* __restrict__ wq, const float* __restrict__ wk,
                                                   const float* __restrict__ wv, const float* __restrict__ wp,
                                                   ushort* __restrict__ wbf){
  int idx = blockIdx.x * 256 + threadIdx.x;
  const float* srcs[4] = {wq, wk, wv, wp};
  #pragma unroll
  for (int m = 0; m < 4; m++){
    float4 v = reinterpret_cast<const float4*>(srcs[m])[idx];
    ushort4 o; o.x = f2bf(v.x); o.y = f2bf(v.y); o.z = f2bf(v.z); o.w = f2bf(v.w);
    reinterpret_cast<ushort4*>(wbf + (size_t)m * CC * CC)[idx] = o;
  }
}

// ---------------- GroupNorm stats ----------------
__global__ __launch_bounds__(256) void k_gn_stats(const float* __restrict__ x, float* __restrict__ stats){
  int bg = blockIdx.x;  // 0..63
  const float* p = x + (size_t)bg * (16 * NN);
  float s = 0.f, ss = 0.f;
  for (int i = threadIdx.x; i < 16 * NN / 4; i += 256){
    float4 v = reinterpret_cast<const float4*>(p)[i];
    s  += v.x + v.y + v.z + v.w;
    ss += v.x*v.x + v.y*v.y + v.z*v.z + v.w*v.w;
  }
  #pragma unroll
  for (int off = 32; off; off >>= 1){ s += __shfl_down(s, off); ss += __shfl_down(ss, off); }
  __shared__ float rs_[4], rss_[4];
  int w = threadIdx.x >> 6, lane = threadIdx.x & 63;
  if (lane == 0){ rs_[w] = s; rss_[w] = ss; }
  __syncthreads();
  if (threadIdx.x == 0){
    float S = rs_[0] + rs_[1] + rs_[2] + rs_[3];
    float SS = rss_[0] + rss_[1] + rss_[2] + rss_[3];
    float inv = 1.0f / (16.0f * NN);
    float mean = S * inv;
    float var = SS * inv - mean * mean;
    stats[bg * 2 + 0] = mean;
    stats[bg * 2 + 1] = rsqrtf(var + EPSV);
  }
}

// ---------------- GN apply + transpose: x[b][c][n] -> hf_t[b][n][c] bf16 ----------------
__global__ __launch_bounds__(256) void k_gn_apply(const float* __restrict__ x, const float* __restrict__ gsc,
                                                  const float* __restrict__ gbi, const float* __restrict__ stats,
                                                  ushort* __restrict__ hf){
  __shared__ ushort tr[32][520];
  int b = blockIdx.y;
  int nb = blockIdx.x * 32;
  int t = threadIdx.x;
  int n = t & 31, cr = t >> 5;
  const float* xb = x + (size_t)b * CC * NN;
  for (int c0 = 0; c0 < CC; c0 += 8){
    int c = c0 + cr;
    float mean = stats[(b * GG + (c >> 4)) * 2 + 0];
    float rstd = stats[(b * GG + (c >> 4)) * 2 + 1];
    float v = xb[(size_t)c * NN + nb + n];
    tr[n][c] = f2bf((v - mean) * rstd * gsc[c] + gbi[c]);
  }
  __syncthreads();
  ushort* out = hf + ((size_t)b * NN + nb) * CC;
  int c8 = (t & 63) * 8;
  int nrow0 = t >> 6;
  #pragma unroll
  for (int i = 0; i < 8; i++){
    int nr = nrow0 + i * 4;
    *reinterpret_cast<s16x8*>(&out[(size_t)nr * CC + c8]) =
      *reinterpret_cast<const s16x8*>(&tr[nr][c8]);
  }
}

// ---------------- fused QKV GEMM: stages hf B-tile once, 3 A-tiles ----------------
// q,k -> bf16 transposed [n][o] (q scaled by rs); v -> bf16 [o][n].
__global__ __launch_bounds__(256) void k_gemm_qkv(const ushort* __restrict__ W, const ushort* __restrict__ Bt,
                                                  const float* __restrict__ bq, const float* __restrict__ bk,
                                                  const float* __restrict__ bv,
                                                  ushort* __restrict__ qo, ushort* __restrict__ ko,
                                                  ushort* __restrict__ vo, float rs){
  __shared__ ushort Al[3][64][72];
  __shared__ ushort Bl[64][72];
  __shared__ float bl[3][64];
  int b = blockIdx.z, ob = blockIdx.y * 64, nb = blockIdx.x * 64;
  int t = threadIdx.x, w = t >> 6, l = t & 63;
  int lr = l & 15, lk = l >> 4;
  int wo = (w >> 1) * 32, wn = (w & 1) * 32;
  if (t < 64){ bl[0][t] = bq[ob + t]; bl[1][t] = bk[ob + t]; bl[2][t] = bv[ob + t]; }
  const ushort* Bp = Bt + ((size_t)b * NN + nb) * CC;
  int srow = t >> 2, scol = (t & 3) * 16;
  f32x4 acc[3][2][2] = {};
  for (int k0 = 0; k0 < CC; k0 += 64){
    #pragma unroll
    for (int m = 0; m < 3; m++){
      const ushort* Ap = W + (size_t)m * CC * CC + (size_t)ob * CC;
      *reinterpret_cast<s16x8*>(&Al[m][srow][scol])     = *reinterpret_cast<const s16x8*>(&Ap[(size_t)srow * CC + k0 + scol]);
      *reinterpret_cast<s16x8*>(&Al[m][srow][scol + 8]) = *reinterpret_cast<const s16x8*>(&Ap[(size_t)srow * CC + k0 + scol + 8]);
    }
    *reinterpret_cast<s16x8*>(&Bl[srow][scol])     = *reinterpret_cast<const s16x8*>(&Bp[(size_t)srow * CC + k0 + scol]);
    *reinterpret_cast<s16x8*>(&Bl[srow][scol + 8]) = *reinterpret_cast<const s16x8*>(&Bp[(size_t)srow * CC + k0 + scol + 8]);
    __syncthreads();
    #pragma unroll
    for (int kk = 0; kk < 2; kk++){
      s16x8 b0 = *reinterpret_cast<const s16x8*>(&Bl[wn + lr][kk * 32 + lk * 8]);
      s16x8 b1 = *reinterpret_cast<const s16x8*>(&Bl[wn + 16 + lr][kk * 32 + lk * 8]);
      #pragma unroll
      for (int m = 0; m < 3; m++){
        s16x8 a0 = *reinterpret_cast<const s16x8*>(&Al[m][wo + lr][kk * 32 + lk * 8]);
        s16x8 a1 = *reinterpret_cast<const s16x8*>(&Al[m][wo + 16 + lr][kk * 32 + lk * 8]);
        acc[m][0][0] = mfma16(a0, b0, acc[m][0][0]);
        acc[m][0][1] = mfma16(a0, b1, acc[m][0][1]);
        acc[m][1][0] = mfma16(a1, b0, acc[m][1][0]);
        acc[m][1][1] = mfma16(a1, b1, acc[m][1][1]);
      }
    }
    __syncthreads();
  }
  // q, k epilogue: transposed [n][o]
  #pragma unroll
  for (int m = 0; m < 2; m++){
    ushort* dst = (m == 0) ? qo : ko;
    float scl = (m == 0) ? rs : 1.0f;
    #pragma unroll
    for (int oi = 0; oi < 2; oi++)
      #pragma unroll
      for (int nj = 0; nj < 2; nj++){
        int o0 = wo + oi * 16 + lk * 4;
        int n  = nb + wn + nj * 16 + lr;
        s16x4 pv;
        #pragma unroll
        for (int r = 0; r < 4; r++) pv[r] = f2bfs((acc[m][oi][nj][r] + bl[m][o0 + r]) * scl);
        *reinterpret_cast<s16x4*>(&dst[((size_t)b * NN + n) * CC + ob + o0]) = pv;
      }
  }
  // v epilogue: [o][n] via LDS transpose (reuse Al[0])
  #pragma unroll
  for (int oi = 0; oi < 2; oi++)
    #pragma unroll
    for (int nj = 0; nj < 2; nj++){
      int o0 = wo + oi * 16 + lk * 4;
      int ncl = wn + nj * 16 + lr;
      #pragma unroll
      for (int r = 0; r < 4; r++) Al[0][o0 + r][ncl] = f2bf(acc[2][oi][nj][r] + bl[2][o0 + r]);
    }
  __syncthreads();
  {
    int o = t >> 2, ns = (t & 3) * 16;
    ushort* dst = &vo[((size_t)b * CC + ob + o) * NN + nb + ns];
    *reinterpret_cast<s16x8*>(dst)     = *reinterpret_cast<const s16x8*>(&Al[0][o][ns]);
    *reinterpret_cast<s16x8*>(dst + 8) = *reinterpret_cast<const s16x8*>(&Al[0][o][ns + 8]);
  }
}

// ---------------- proj GEMM: fp32 out + residual ----------------
__global__ __launch_bounds__(256) void k_gemm_proj(const ushort* __restrict__ A, const ushort* __restrict__ Bt,
                                                   const float* __restrict__ bias, float* __restrict__ o32,
                                                   const float* __restrict__ xres){
  __shared__ ushort Al[64][72];
  __shared__ ushort Bl[64][72];
  __shared__ float bl[64];
  __shared__ float trf[64 * 68];
  int b = blockIdx.z, ob = blockIdx.y * 64, nb = blockIdx.x * 64;
  int t = threadIdx.x, w = t >> 6, l = t & 63;
  int lr = l & 15, lk = l >> 4;
  int wo = (w >> 1) * 32, wn = (w & 1) * 32;
  if (t < 64) bl[t] = bias[ob + t];
  const ushort* Bp = Bt + ((size_t)b * NN + nb) * CC;
  const ushort* Ap = A + (size_t)ob * CC;
  int srow = t >> 2, scol = (t & 3) * 16;
  f32x4 acc[2][2] = {};
  for (int k0 = 0; k0 < CC; k0 += 64){
    *reinterpret_cast<s16x8*>(&Al[srow][scol])     = *reinterpret_cast<const s16x8*>(&Ap[(size_t)srow * CC + k0 + scol]);
    *reinterpret_cast<s16x8*>(&Al[srow][scol + 8]) = *reinterpret_cast<const s16x8*>(&Ap[(size_t)srow * CC + k0 + scol + 8]);
    *reinterpret_cast<s16x8*>(&Bl[srow][scol])     = *reinterpret_cast<const s16x8*>(&Bp[(size_t)srow * CC + k0 + scol]);
    *reinterpret_cast<s16x8*>(&Bl[srow][scol + 8]) = *reinterpret_cast<const s16x8*>(&Bp[(size_t)srow * CC + k0 + scol + 8]);
    __syncthreads();
    #pragma unroll
    for (int kk = 0; kk < 2; kk++){
      s16x8 a0 = *reinterpret_cast<const s16x8*>(&Al[wo + lr][kk * 32 + lk * 8]);
      s16x8 a1 = *reinterpret_cast<const s16x8*>(&Al[wo + 16 + lr][kk * 32 + lk * 8]);
      s16x8 b0 = *reinterpret_cast<const s16x8*>(&Bl[wn + lr][kk * 32 + lk * 8]);
      s16x8 b1 = *reinterpret_cast<const s16x8*>(&Bl[wn + 16 + lr][kk * 32 + lk * 8]);
      acc[0][0] = mfma16(a0, b0, acc[0][0]);
      acc[0][1] = mfma16(a0, b1, acc[0][1]);
      acc[1][0] = mfma16(a1, b0, acc[1][0]);
      acc[1][1] = mfma16(a1, b1, acc[1][1]);
    }
    __syncthreads();
  }
  #pragma unroll
  for (int oi = 0; oi < 2; oi++)
    #pragma unroll
    for (int nj = 0; nj < 2; nj++){
      int o0 = wo + oi * 16 + lk * 4;
      int ncl = wn + nj * 16 + lr;
      #pragma unroll
      for (int r = 0; r < 4; r++) trf[(o0 + r) * 68 + ncl] = acc[oi][nj][r] + bl[o0 + r];
    }
  __syncthreads();
  {
    int o = t >> 2, ns = (t & 3) * 16;
    size_t base = ((size_t)b * CC + ob + o) * NN + nb + ns;
    #pragma unroll
    for (int q = 0; q < 4; q++){
      float4 xv = *reinterpret_cast<const float4*>(&xres[base + q * 4]);
      float4 ov;
      ov.x = xv.x + trf[o * 68 + ns + q * 4 + 0];
      ov.y = xv.y + trf[o * 68 + ns + q * 4 + 1];
      ov.z = xv.z + trf[o * 68 + ns + q * 4 + 2];
      ov.w = xv.w + trf[o * 68 + ns + q * 4 + 3];
      *reinterpret_cast<float4*>(&o32[base + q * 4]) = ov;
    }
  }
}

// ---------------- flash attention v4: R2 structure + defer-max + 4-way ILP ----------------
__global__ __launch_bounds__(256, 2) void k_attn2(const ushort* __restrict__ qt, const ushort* __restrict__ kt,
                                                  const ushort* __restrict__ vv, ushort* __restrict__ ot,
                                                  float* __restrict__ opart, float* __restrict__ mpart,
                                                  float* __restrict__ lpart, int nsplit){
  __shared__ ushort Kl[2][32][512];   // rows 1KB; LDS[j][x] holds K[j][x ^ (j&7)] (16B chunks)
  __shared__ ushort Pl[64][40];
  __shared__ float cl[64], llds[64];
  __shared__ int sfl[4];
  int b = blockIdx.z, s = blockIdx.y, ib = blockIdx.x * 64;
  int t = threadIdx.x, w = t >> 6, l = t & 63;
  int lr = l & 15, lk = l >> 4;
  int jlen = NN / nsplit;
  int jbase = s * jlen;
  int niter = jlen / 32;
  const ushort* qb = qt + ((size_t)b * NN + ib) * CC;
  const ushort* kb = kt + (size_t)b * NN * CC;
  const ushort* vb = vv + (size_t)b * CC * NN;

  s16x8 qf[16];
  #pragma unroll
  for (int k = 0; k < 16; k++)
    qf[k] = *reinterpret_cast<const s16x8*>(&qb[(size_t)(w * 16 + lr) * CC + k * 32 + lk * 8]);

  f32x4 oc[8][4] = {};   // [ct][it]: O[c = w*128+ct*16+lk*4+r][i = it*16+lr]
  float m_run = -1e30f, l_run = 0.f;

  #pragma unroll
  for (int q = 0; q < 8; q++){
    int j = q * 4 + w;
    const ushort* src = kb + (size_t)(jbase + j) * CC + ((l ^ (j & 7)) << 3);
    GLOAD_LDS16(src, &Kl[0][j][0]);
  }
  __syncthreads();
  int cur = 0;
  for (int it = 0; it < niter; it++){
    int j0 = jbase + it * 32;
    if (it + 1 < niter){
      #pragma unroll
      for (int q = 0; q < 8; q++){
        int j = q * 4 + w;
        const ushort* src = kb + (size_t)(j0 + 32 + j) * CC + ((l ^ (j & 7)) << 3);
        GLOAD_LDS16(src, &Kl[cur ^ 1][j][0]);
      }
    }
    // S^T = K.Q : 4-way ILP (even/odd k partials)
    f32x4 sa0 = {0.f,0.f,0.f,0.f}, sa1 = {0.f,0.f,0.f,0.f};
    f32x4 sb0 = {0.f,0.f,0.f,0.f}, sb1 = {0.f,0.f,0.f,0.f};
    #pragma unroll
    for (int k = 0; k < 16; k += 2){
      int x0 = ((k * 4 + lk) ^ (lr & 7)) << 3;
      int x1 = (((k + 1) * 4 + lk) ^ (lr & 7)) << 3;
      s16x8 k00 = *reinterpret_cast<const s16x8*>(&Kl[cur][lr][x0]);
      s16x8 k10 = *reinterpret_cast<const s16x8*>(&Kl[cur][16 + lr][x0]);
      s16x8 k01 = *reinterpret_cast<const s16x8*>(&Kl[cur][lr][x1]);
      s16x8 k11 = *reinterpret_cast<const s16x8*>(&Kl[cur][16 + lr][x1]);
      sa0 = mfma16(k00, qf[k], sa0);
      sb0 = mfma16(k10, qf[k], sb0);
      sa1 = mfma16(k01, qf[k + 1], sa1);
      sb1 = mfma16(k11, qf[k + 1], sb1);
    }
    f32x4 sa, sb;
    #pragma unroll
    for (int r = 0; r < 4; r++){ sa[r] = sa0[r] + sa1[r]; sb[r] = sb0[r] + sb1[r]; }
    // in-register online softmax with defer-max (THR=8)
    float mx = fmaxf(fmaxf(fmaxf(sa[0], sa[1]), fmaxf(sa[2], sa[3])),
                     fmaxf(fmaxf(sb[0], sb[1]), fmaxf(sb[2], sb[3])));
    mx = fmaxf(mx, __shfl_xor(mx, 16));
    mx = fmaxf(mx, __shfl_xor(mx, 32));
    int need = __any(mx - m_run > 8.0f);
    float corr = 1.0f;
    if (need){
      float mnew = fmaxf(m_run, mx);
      corr = __expf(m_run - mnew);
      m_run = mnew;
    }
    float p[8];
    p[0] = __expf(sa[0] - m_run); p[1] = __expf(sa[1] - m_run);
    p[2] = __expf(sa[2] - m_run); p[3] = __expf(sa[3] - m_run);
    p[4] = __expf(sb[0] - m_run); p[5] = __expf(sb[1] - m_run);
    p[6] = __expf(sb[2] - m_run); p[7] = __expf(sb[3] - m_run);
    float ls = (p[0] + p[1]) + (p[2] + p[3]) + (p[4] + p[5]) + (p[6] + p[7]);
    ls += __shfl_xor(ls, 16);
    ls += __shfl_xor(ls, 32);
    l_run = l_run * corr + ls;
    s16x4 pA, pB;
    #pragma unroll
    for (int r = 0; r < 4; r++){ pA[r] = f2bfs(p[r]); pB[r] = f2bfs(p[4 + r]); }
    *reinterpret_cast<s16x4*>(&Pl[w * 16 + lr][lk * 4])      = pA;
    *reinterpret_cast<s16x4*>(&Pl[w * 16 + lr][16 + lk * 4]) = pB;
    if (lk == 0) cl[w * 16 + lr] = corr;
    if (l == 0)  sfl[w] = need;
    __syncthreads();
    // rescale O only when some wave's running max moved
    if (sfl[0] | sfl[1] | sfl[2] | sfl[3]){
      float cr0 = cl[lr], cr1 = cl[16 + lr], cr2 = cl[32 + lr], cr3 = cl[48 + lr];
      #pragma unroll
      for (int ct = 0; ct < 8; ct++){
        #pragma unroll
        for (int r = 0; r < 4; r++){
          oc[ct][0][r] *= cr0; oc[ct][1][r] *= cr1;
          oc[ct][2][r] *= cr2; oc[ct][3][r] *= cr3;
        }
      }
    }
    s16x8 pf[4];
    #pragma unroll
    for (int it4 = 0; it4 < 4; it4++)
      pf[it4] = *reinterpret_cast<const s16x8*>(&Pl[it4 * 16 + lr][lk * 8]);
    // PV: V fragment loaded per-ct (short live range; compiler pipelines loads vs MFMAs)
    #pragma unroll
    for (int ct = 0; ct < 8; ct++){
      s16x8 vf = *reinterpret_cast<const s16x8*>(&vb[(size_t)(w * 128 + ct * 16 + lr) * NN + j0 + lk * 8]);
      #pragma unroll
      for (int it4 = 0; it4 < 4; it4++)
        oc[ct][it4] = mfma16(vf, pf[it4], oc[ct][it4]);
    }
    __syncthreads();
    cur ^= 1;
  }
  if (lk == 0) llds[w * 16 + lr] = l_run;
  __syncthreads();
  if (nsplit == 1){
    #pragma unroll
    for (int it4 = 0; it4 < 4; it4++){
      float linv = 1.0f / llds[it4 * 16 + lr];
      #pragma unroll
      for (int ct = 0; ct < 8; ct++){
        s16x4 ov;
        #pragma unroll
        for (int r = 0; r < 4; r++) ov[r] = f2bfs(oc[ct][it4][r] * linv);
        *reinterpret_cast<s16x4*>(&ot[((size_t)b * NN + ib + it4 * 16 + lr) * CC + w * 128 + ct * 16 + lk * 4]) = ov;
      }
    }
  } else {
    #pragma unroll
    for (int it4 = 0; it4 < 4; it4++){
      size_t nrow = (size_t)(s * BB + b) * NN + ib + it4 * 16 + lr;
      #pragma unroll
      for (int ct = 0; ct < 8; ct++){
        f32x4 ov = oc[ct][it4];
        *reinterpret_cast<f32x4*>(&opart[nrow * CC + w * 128 + ct * 16 + lk * 4]) = ov;
      }
    }
    if (lk == 0){
      mpart[(size_t)(s * BB + b) * NN + ib + w * 16 + lr] = m_run;
      lpart[(size_t)(s * BB + b) * NN + ib + w * 16 + lr] = l_run;
    }
  }
}

// ---------------- combine j-split partials ----------------
__global__ __launch_bounds__(128) void k_combine(const float* __restrict__ opart, const float* __restrict__ mpart,
                                                 const float* __restrict__ lpart, ushort* __restrict__ ot, int S){
  int n = blockIdx.x, b = blockIdx.y;
  float M = -1e30f;
  for (int s = 0; s < S; s++) M = fmaxf(M, mpart[(size_t)(s * BB + b) * NN + n]);
  float L = 0.f;
  for (int s = 0; s < S; s++)
    L += lpart[(size_t)(s * BB + b) * NN + n] * __expf(mpart[(size_t)(s * BB + b) * NN + n] - M);
  float linv = 1.0f / L;
  int c = threadIdx.x * 4;
  f32x4 acc = {0.f, 0.f, 0.f, 0.f};
  for (int s = 0; s < S; s++){
    float wgt = __expf(mpart[(size_t)(s * BB + b) * NN + n] - M);
    f32x4 v = *reinterpret_cast<const f32x4*>(&opart[((size_t)(s * BB + b) * NN + n) * CC + c]);
    acc[0] += v[0] * wgt; acc[1] += v[1] * wgt; acc[2] += v[2] * wgt; acc[3] += v[3] * wgt;
  }
  s16x4 ov;
  #pragma unroll
  for (int r = 0; r < 4; r++) ov[r] = f2bfs(acc[r] * linv);
  *reinterpret_cast<s16x4*>(&ot[((size_t)b * NN + n) * CC + c]) = ov;
}

extern "C" void kernel_launch(void* const* d_in, const int* in_sizes, int n_in,
                              void* d_out, int out_size, void* d_ws, size_t ws_size,
                              hipStream_t stream){
  const float* x   = (const float*)d_in[0];
  const float* gsc = (const float*)d_in[1];
  const float* gbi = (const float*)d_in[2];
  const float* wq  = (const float*)d_in[3];
  const float* bq  = (const float*)d_in[4];
  const float* wk  = (const float*)d_in[5];
  const float* bk  = (const float*)d_in[6];
  const float* wv  = (const float*)d_in[7];
  const float* bv  = (const float*)d_in[8];
  const float* wp  = (const float*)d_in[9];
  const float* bp  = (const float*)d_in[10];
  char* ws = (char*)d_ws;
  const size_t MB = 1024 * 1024;
  ushort* wbf = (ushort*)ws;                       // 2 MB
  ushort* qtb = (ushort*)(ws + 2 * MB);            // 8 MB: q^T [b][n][c] (pre-scaled)
  ushort* ktb = (ushort*)(ws + 10 * MB);           // 8 MB: k^T [b][n][c]
  ushort* vvb = (ushort*)(ws + 18 * MB);           // 8 MB: v   [b][c][n]
  ushort* hfb = (ushort*)(ws + 26 * MB);           // 8 MB: hf^T / attn-out [b][n][c]
  float* stats = (float*)(ws + 34 * MB);           // 512 B
  float* mpart = (float*)(ws + 34 * MB + 4096);
  float* lpart = (float*)(ws + 34 * MB + 300 * 1024);
  float* opart = (float*)(ws + 35 * MB);           // S*16 MB
  ushort* otb = hfb;

  int S = (ws_size >= 99 * MB) ? 4 : (ws_size >= 67 * MB) ? 2 : 1;
  const float rs = 0.044194173824159216f;  // 512^-0.5

  k_convert_w<<<256, 256, 0, stream>>>(wq, wk, wv, wp, wbf);
  k_gn_stats<<<64, 256, 0, stream>>>(x, stats);
  k_gn_apply<<<dim3(128, 2, 1), 256, 0, stream>>>(x, gsc, gbi, stats, hfb);
  k_gemm_qkv<<<dim3(64, 8, 2), 256, 0, stream>>>(wbf, hfb, bq, bk, bv, qtb, ktb, vvb, rs);
  k_attn2<<<dim3(64, S, 2), 256, 0, stream>>>(qtb, ktb, vvb, otb, opart, mpart, lpart, S);
  if (S > 1)
    k_combine<<<dim3(NN, 2, 1), 128, 0, stream>>>(opart, mpart, lpart, otb, S);
  k_gemm_proj<<<dim3(64, 8, 2), 256, 0, stream>>>(wbf + 3 * CC * CC, otb, bp, (float*)d_out, x);
}